// Round 7
// baseline (209.133 us; speedup 1.0000x reference)
//
#include <hip/hip_runtime.h>
#include <cstdint>

// B,D,H,W,C = 4,8,16,16,512; R=64; F=256; rows=8192; keys/batch=2048.
// Inputs f32, output f32. GEMMs via mfma_f32_16x16x32_bf16, frag-ordered panels.
// K-loops are barrier-free: per-wave glds double-buffer + s_waitcnt vmcnt(0).
#define LN_EPS 1e-3f
using u16 = unsigned short;
using u32 = unsigned int;
typedef __attribute__((ext_vector_type(8))) short bh8;   // 8 bf16
typedef __attribute__((ext_vector_type(4))) float f4;    // 4 f32 acc
#define MFMA16(A,B,C) __builtin_amdgcn_mfma_f32_16x16x32_bf16((A),(B),(C),0,0,0)
#define WAITV0 __builtin_amdgcn_s_waitcnt(0x0F70)   // vmcnt(0), ignore lgkm/exp

__device__ __forceinline__ u16 bf16r(float f){
    union{float f;u32 u;} c; c.f=f;
    return (u16)((c.u + 0x7fffu + ((c.u>>16)&1u))>>16);
}
__device__ __forceinline__ u32 pk2(float a, float b){
    return (u32)bf16r(a) | ((u32)bf16r(b)<<16);
}
__device__ __forceinline__ void glds16(const void* g, void* l){
    __builtin_amdgcn_global_load_lds(
        (const __attribute__((address_space(1))) u32*)g,
        (__attribute__((address_space(3))) u32*)l, 16, 0, 0);
}

// ---------------- K0: repack f32 -> bf16 frag-ordered K-panels ----------------
__global__ __launch_bounds__(256) void k0_prep(
    const float* __restrict__ x,  const float* __restrict__ wq, const float* __restrict__ wk,
    const float* __restrict__ wv, const float* __restrict__ wm,
    u16* __restrict__ x_pB, u16* __restrict__ wv_p, u16* __restrict__ wm_p, u16* __restrict__ wqk_p)
{
    const int t = threadIdx.x;
    const int c = t & 15, qn = t >> 4;
    const int quad = qn & 3, ntl = qn >> 2;
    const int blk = blockIdx.x;
    if (blk < 256){
        const int bd = blk >> 3, s = blk & 7;
        const float* src = x + ((size_t)(bd*256 + s*32 + quad*8))*512;
        u16* dst = x_pB + (size_t)(bd*8+s)*16384;
        #pragma unroll
        for (int i=0;i<8;++i){
            int nt = i*4 + ntl, n = nt*16 + c;
            float v[8];
            #pragma unroll
            for (int j=0;j<8;++j) v[j] = src[(size_t)j*512 + n];
            uint4 o; o.x=pk2(v[0],v[1]); o.y=pk2(v[2],v[3]); o.z=pk2(v[4],v[5]); o.w=pk2(v[6],v[7]);
            *(uint4*)&dst[((nt*4+quad)*16 + c)*8] = o;
        }
    } else if (blk < 288){
        const int ism = (blk >= 272);
        const int s = ism ? (blk-272) : (blk-256);
        const float* src = (ism ? wm : wv) + (size_t)(s*32 + quad*8)*512;
        u16* dst = (ism ? wm_p : wv_p) + (size_t)s*16384;
        #pragma unroll
        for (int i=0;i<8;++i){
            int nt = i*4 + ntl, n = nt*16 + c;
            float v[8];
            #pragma unroll
            for (int j=0;j<8;++j) v[j] = src[(size_t)j*512 + n];
            uint4 o; o.x=pk2(v[0],v[1]); o.y=pk2(v[2],v[3]); o.z=pk2(v[4],v[5]); o.w=pk2(v[6],v[7]);
            *(uint4*)&dst[((nt*4+quad)*16 + c)*8] = o;
        }
    } else {
        const int s = blk - 288;
        u16* dst = wqk_p + (size_t)s*4096;
        #pragma unroll
        for (int i=0;i<2;++i){
            int nt = i*4 + ntl, n = nt*16 + c;
            const float* src = (n < 64) ? (wq + (size_t)(s*32 + quad*8)*64 + n)
                                        : (wk + (size_t)(s*32 + quad*8)*64 + (n-64));
            float v[8];
            #pragma unroll
            for (int j=0;j<8;++j) v[j] = src[(size_t)j*64];
            uint4 o; o.x=pk2(v[0],v[1]); o.y=pk2(v[2],v[3]); o.z=pk2(v[4],v[5]); o.w=pk2(v[6],v[7]);
            *(uint4*)&dst[((nt*4+quad)*16 + c)*8] = o;
        }
    }
}

// ---------------- K1: Q/K projection (MFMA, barrier-free K-loop) ----------------
// grid 512 (16 rows/block). A staged once (16 KB); wqk panels per-wave dbuf.
__global__ __launch_bounds__(256) void k1_qk(
    const float* __restrict__ x, const float* __restrict__ bq, const float* __restrict__ bk,
    const u16* __restrict__ wqk_p, u16* __restrict__ Qb, u16* __restrict__ Kb)
{
    __shared__ u16 Asf[8192];      // 16 rows x 512 K, A-frag [s][quad][c][8]
    __shared__ u16 Bsf[2][4096];   // dbuf; wave-local 2 KB quarters
    const int t = threadIdx.x, w = t>>6, lane = t&63, quad = lane>>4, c = lane&15;
    const int rowbase = blockIdx.x << 4;
    // stage full A tile, frag order
    #pragma unroll
    for (int i=0;i<8;++i){
        int idx = t + (i<<8);            // 0..2047 (float4 units)
        int fr = idx >> 7, fc4 = idx & 127;
        float4 xv = *(const float4*)&x[(size_t)(rowbase+fr)*512 + fc4*4];
        uint2 pkv; pkv.x = pk2(xv.x,xv.y); pkv.y = pk2(xv.z,xv.w);
        int s = fc4 >> 3, qd = (fc4 >> 1) & 3, j0 = (fc4 & 1)*4;
        *(uint2*)&Asf[s*512 + (qd*16 + fr)*8 + j0] = pkv;
    }
    // prefetch s=0 panels into buf 0
    #pragma unroll
    for (int i=0;i<2;++i)
        glds16((const char*)wqk_p + (w*2+i)*1024 + lane*16, (char*)Bsf + (w*2+i)*1024);
    __syncthreads();
    f4 acc[2] = { {0.f,0.f,0.f,0.f}, {0.f,0.f,0.f,0.f} };
    int buf = 0;
    for (int s=0;s<16;++s){
        WAITV0;
        if (s < 15){
            #pragma unroll
            for (int i=0;i<2;++i)
                glds16((const char*)wqk_p + (size_t)(s+1)*8192 + (w*2+i)*1024 + lane*16,
                       (char*)Bsf + (buf^1)*8192 + (w*2+i)*1024);
        }
        bh8 a = *(const bh8*)&Asf[s*512 + (quad*16+c)*8];
        #pragma unroll
        for (int nt=0;nt<2;++nt){
            bh8 b = *(const bh8*)&Bsf[buf][(w*2+nt)*512 + (quad*16+c)*8];
            acc[nt] = MFMA16(a, b, acc[nt]);
        }
        buf ^= 1;
    }
    const int rt = blockIdx.x;
    #pragma unroll
    for (int nt=0;nt<2;++nt){
        int cqk = w*32 + nt*16 + c;
        bool isQ = (cqk < 64);
        int r = isQ ? cqk : (cqk - 64);
        float bias = isQ ? bq[r] : bk[r];
        int kh = r>>5, q2 = (r>>3)&3, j = r&7;
        u16* dstb = (isQ ? Qb : Kb) + (size_t)((rt*2 + kh)*4 + q2)*128 + j;
        #pragma unroll
        for (int reg=0;reg<4;++reg){
            int cp = quad*4 + reg;
            dstb[cp*8] = bf16r(acc[nt][reg] + bias);
        }
    }
}

// ---------------- K234: attn + LN + MLP + LN, fully fused ----------------
// grid 512 = (b,d,ft16), block 256 (4 waves). All K-loops barrier-free
// (per-wave staging quarters, dbuf, vmcnt waits). y1 kept in regs + zf frags.
__global__ __launch_bounds__(256) void k234(
    const u16* __restrict__ Qb, const u16* __restrict__ Kb,
    const u16* __restrict__ x_pB, const u16* __restrict__ wv_p, const u16* __restrict__ wm_p,
    const float* __restrict__ x, const float* __restrict__ bv,
    const float* __restrict__ g1, const float* __restrict__ b1,
    const float* __restrict__ bm, const float* __restrict__ g2, const float* __restrict__ b2,
    float* __restrict__ out)
{
    __shared__ u16 Bs[2][8192];     // 32 KB dbuf; wave-local 4 KB quarters
    __shared__ u16 zf[8192];        // 16 KB: z, then y1 (A-frag over K=512)
    __shared__ u16 a2f[4096];       // 8 KB (A-frag over K=256)
    __shared__ u16 qsf[1024];       // 2 KB
    __shared__ float redA[4][16], redB[4][16];
    const int t = threadIdx.x, w = t>>6, lane = t&63, quad = lane>>4, c = lane&15;
    const int b = blockIdx.x >> 7, rem = blockIdx.x & 127, d = rem >> 4, ft = rem & 15;
    const int bd = b*8 + d, rowbase = (bd<<8) + (ft<<4), rt = rowbase >> 4;
    const char* Kbase = (const char*)Kb + (size_t)b*262144;
    const char* xpb   = (const char*)x_pB + (size_t)bd*262144;

    // prologue: Q frags + phase-A chunk 0
    if (w < 2) glds16((const char*)Qb + (size_t)rt*2048 + w*1024 + lane*16, (char*)qsf + w*1024);
    #pragma unroll
    for (int i=0;i<4;++i)
        glds16(Kbase + (w*4+i)*1024 + lane*16, (char*)Bs + (w*4+i)*1024);
    __syncthreads();
    bh8 aq0 = *(const bh8*)&qsf[(quad*16+c)*8];
    bh8 aq1 = *(const bh8*)&qsf[512 + (quad*16+c)*8];

    float lp[4] = {0.f,0.f,0.f,0.f};
    float a2r[4][2][2];
    #pragma unroll
    for (int r=0;r<4;++r){ a2r[r][0][0]=0.f; a2r[r][0][1]=0.f; a2r[r][1][0]=0.f; a2r[r][1][1]=0.f; }
    int buf = 0;

    // ---- Phase A: scores + exp + g-fold (16 chunks of 128 keys)
    for (int cc=0; cc<16; ++cc){
        WAITV0;
        if (cc < 15){
            #pragma unroll
            for (int i=0;i<4;++i)
                glds16(Kbase + (size_t)(cc+1)*16384 + (w*4+i)*1024 + lane*16,
                       (char*)Bs + (buf^1)*16384 + (w*4+i)*1024);
        } else {  // prefetch phase B (s=0,h=0)
            #pragma unroll
            for (int i=0;i<4;++i)
                glds16(xpb + (w*8+i)*1024 + lane*16,
                       (char*)Bs + (buf^1)*16384 + (w*4+i)*1024);
        }
        f4 sa[2] = { {0.f,0.f,0.f,0.f}, {0.f,0.f,0.f,0.f} };
        #pragma unroll
        for (int kt=0;kt<2;++kt){
            bh8 b0 = *(const bh8*)&Bs[buf][(w*2+kt)*1024 +       (quad*16+c)*8];
            bh8 b1v= *(const bh8*)&Bs[buf][(w*2+kt)*1024 + 512 + (quad*16+c)*8];
            sa[kt] = MFMA16(aq0, b0, sa[kt]);
            sa[kt] = MFMA16(aq1, b1v, sa[kt]);
        }
        const int h = cc & 1;
        #pragma unroll
        for (int kt=0;kt<2;++kt)
            #pragma unroll
            for (int reg=0;reg<4;++reg){
                float e = __expf(sa[kt][reg]);
                lp[reg] += e;
                a2r[reg][h][kt] += e;
            }
        buf ^= 1;
    }
    // softmax denominator
    #pragma unroll
    for (int reg=0;reg<4;++reg){
        float v = lp[reg];
        v += __shfl_xor(v,1,64); v += __shfl_xor(v,2,64);
        v += __shfl_xor(v,4,64); v += __shfl_xor(v,8,64);
        lp[reg] = v;
    }
    if (c==0){
        #pragma unroll
        for (int reg=0;reg<4;++reg) redA[w][quad*4+reg] = lp[reg];
    }
    __syncthreads();
    float fac[4];
    #pragma unroll
    for (int reg=0;reg<4;++reg){
        int q = quad*4+reg;
        fac[reg] = 1.f/(redA[0][q]+redA[1][q]+redA[2][q]+redA[3][q]);
    }
    #pragma unroll
    for (int reg=0;reg<4;++reg){
        int q = quad*4+reg;
        #pragma unroll
        for (int h=0;h<2;++h)
            #pragma unroll
            for (int kt=0;kt<2;++kt){
                int j = h*128 + (w*2+kt)*16 + c;
                a2f[(j>>5)*512 + (((j>>3)&3)*16 + q)*8 + (j&7)] = bf16r(a2r[reg][h][kt]*fac[reg]);
            }
    }
    __syncthreads();

    // ---- Phase B: z = a2 @ x_bd (K=256 -> 16 half-steps)
    f4 zacc[8];
    #pragma unroll
    for (int nt=0;nt<8;++nt) zacc[nt] = (f4){0.f,0.f,0.f,0.f};
    for (int u=0; u<16; ++u){
        WAITV0;
        const int s = u>>1, h = u&1;
        if (u < 15){
            const int un=u+1, sn=un>>1, hn=un&1;
            #pragma unroll
            for (int i=0;i<4;++i)
                glds16(xpb + (size_t)sn*32768 + (w*8+hn*4+i)*1024 + lane*16,
                       (char*)Bs + (buf^1)*16384 + (w*4+i)*1024);
        } else {  // prefetch phase C (s=0,h=0)
            #pragma unroll
            for (int i=0;i<4;++i)
                glds16((const char*)wv_p + (w*8+i)*1024 + lane*16,
                       (char*)Bs + (buf^1)*16384 + (w*4+i)*1024);
        }
        bh8 a = *(const bh8*)&a2f[s*512 + (quad*16+c)*8];
        #pragma unroll
        for (int j=0;j<4;++j){
            bh8 bb = *(const bh8*)&Bs[buf][((w*4+j)*4+quad)*128 + c*8];
            zacc[h*4+j] = MFMA16(a, bb, zacc[h*4+j]);
        }
        buf ^= 1;
    }
    // z -> zf (A-frag order)
    #pragma unroll
    for (int nt=0;nt<8;++nt)
        #pragma unroll
        for (int reg=0;reg<4;++reg){
            int col = w*128 + nt*16 + c;
            zf[(col>>5)*512 + (((col>>3)&3)*16 + quad*4+reg)*8 + (col&7)] = bf16r(zacc[nt][reg]);
        }
    __syncthreads();

    // ---- Phase C: attn = z @ wv (K=512 -> 32 half-steps)
    f4 cacc[8];
    #pragma unroll
    for (int nt=0;nt<8;++nt) cacc[nt] = (f4){0.f,0.f,0.f,0.f};
    for (int u=0; u<32; ++u){
        WAITV0;
        const int s = u>>1, h = u&1;
        if (u < 31){
            const int un=u+1, sn=un>>1, hn=un&1;
            #pragma unroll
            for (int i=0;i<4;++i)
                glds16((const char*)wv_p + (size_t)sn*32768 + (w*8+hn*4+i)*1024 + lane*16,
                       (char*)Bs + (buf^1)*16384 + (w*4+i)*1024);
        } else {  // prefetch phase D (s=0,h=0)
            #pragma unroll
            for (int i=0;i<4;++i)
                glds16((const char*)wm_p + (w*8+i)*1024 + lane*16,
                       (char*)Bs + (buf^1)*16384 + (w*4+i)*1024);
        }
        bh8 a = *(const bh8*)&zf[s*512 + (quad*16+c)*8];
        #pragma unroll
        for (int j=0;j<4;++j){
            bh8 bb = *(const bh8*)&Bs[buf][((w*4+j)*4+quad)*128 + c*8];
            cacc[h*4+j] = MFMA16(a, bb, cacc[h*4+j]);
        }
        buf ^= 1;
    }
    // epilogue 1: + bv + x residual, LN -> y1 (kept in cacc f32 and zf bf16)
    {
        float sv[4] = {0.f,0.f,0.f,0.f}, qv2[4] = {0.f,0.f,0.f,0.f};
        #pragma unroll
        for (int nt=0;nt<8;++nt){
            int col = w*128 + nt*16 + c;
            float bvv = bv[col];
            #pragma unroll
            for (int reg=0;reg<4;++reg){
                int row = rowbase + quad*4 + reg;
                float val = cacc[nt][reg] + bvv + x[(size_t)row*512 + col];
                cacc[nt][reg] = val;
                sv[reg] += val; qv2[reg] = fmaf(val,val,qv2[reg]);
            }
        }
        #pragma unroll
        for (int reg=0;reg<4;++reg){
            float s1=sv[reg], s2=qv2[reg];
            s1 += __shfl_xor(s1,1,64); s2 += __shfl_xor(s2,1,64);
            s1 += __shfl_xor(s1,2,64); s2 += __shfl_xor(s2,2,64);
            s1 += __shfl_xor(s1,4,64); s2 += __shfl_xor(s2,4,64);
            s1 += __shfl_xor(s1,8,64); s2 += __shfl_xor(s2,8,64);
            sv[reg]=s1; qv2[reg]=s2;
        }
        if (c==0){
            #pragma unroll
            for (int reg=0;reg<4;++reg){ redA[w][quad*4+reg]=sv[reg]; redB[w][quad*4+reg]=qv2[reg]; }
        }
        __syncthreads();
        float mean[4], rstd[4];
        #pragma unroll
        for (int reg=0;reg<4;++reg){
            int q = quad*4+reg;
            float S  = redA[0][q]+redA[1][q]+redA[2][q]+redA[3][q];
            float Q2 = redB[0][q]+redB[1][q]+redB[2][q]+redB[3][q];
            float m = S*(1.f/512.f);
            float var = Q2*(1.f/512.f) - m*m;
            mean[reg]=m; rstd[reg]=rsqrtf(var + LN_EPS);
        }
        __syncthreads();   // redA/redB reads done before reuse in epilogue 2
        #pragma unroll
        for (int nt=0;nt<8;++nt){
            int col = w*128 + nt*16 + c;
            float gg = g1[col], bb1 = b1[col];
            #pragma unroll
            for (int reg=0;reg<4;++reg){
                float y = (cacc[nt][reg]-mean[reg])*rstd[reg]*gg + bb1;
                cacc[nt][reg] = y;
                zf[(col>>5)*512 + (((col>>3)&3)*16 + quad*4+reg)*8 + (col&7)] = bf16r(y);
            }
        }
        __syncthreads();   // zf (y1 frags) visible to all waves
    }

    // ---- Phase D: mlp = y1 @ wm (K=512 -> 32 half-steps)
    f4 dacc[8];
    #pragma unroll
    for (int nt=0;nt<8;++nt) dacc[nt] = (f4){0.f,0.f,0.f,0.f};
    for (int u=0; u<32; ++u){
        WAITV0;
        const int s = u>>1, h = u&1;
        if (u < 31){
            const int un=u+1, sn=un>>1, hn=un&1;
            #pragma unroll
            for (int i=0;i<4;++i)
                glds16((const char*)wm_p + (size_t)sn*32768 + (w*8+hn*4+i)*1024 + lane*16,
                       (char*)Bs + (buf^1)*16384 + (w*4+i)*1024);
        }
        bh8 a = *(const bh8*)&zf[s*512 + (quad*16+c)*8];
        #pragma unroll
        for (int j=0;j<4;++j){
            bh8 bb = *(const bh8*)&Bs[buf][((w*4+j)*4+quad)*128 + c*8];
            dacc[h*4+j] = MFMA16(a, bb, dacc[h*4+j]);
        }
        buf ^= 1;
    }
    // epilogue 2: relu(+bm) + y1 residual, LN -> out
    {
        float sv[4] = {0.f,0.f,0.f,0.f}, qv2[4] = {0.f,0.f,0.f,0.f};
        #pragma unroll
        for (int nt=0;nt<8;++nt){
            int col = w*128 + nt*16 + c;
            float bmv = bm[col];
            #pragma unroll
            for (int reg=0;reg<4;++reg){
                float hh = fmaxf(dacc[nt][reg]+bmv, 0.f) + cacc[nt][reg];
                dacc[nt][reg] = hh;
                sv[reg] += hh; qv2[reg] = fmaf(hh,hh,qv2[reg]);
            }
        }
        #pragma unroll
        for (int reg=0;reg<4;++reg){
            float s1=sv[reg], s2=qv2[reg];
            s1 += __shfl_xor(s1,1,64); s2 += __shfl_xor(s2,1,64);
            s1 += __shfl_xor(s1,2,64); s2 += __shfl_xor(s2,2,64);
            s1 += __shfl_xor(s1,4,64); s2 += __shfl_xor(s2,4,64);
            s1 += __shfl_xor(s1,8,64); s2 += __shfl_xor(s2,8,64);
            sv[reg]=s1; qv2[reg]=s2;
        }
        if (c==0){
            #pragma unroll
            for (int reg=0;reg<4;++reg){ redA[w][quad*4+reg]=sv[reg]; redB[w][quad*4+reg]=qv2[reg]; }
        }
        __syncthreads();
        float mean[4], rstd[4];
        #pragma unroll
        for (int reg=0;reg<4;++reg){
            int q = quad*4+reg;
            float S  = redA[0][q]+redA[1][q]+redA[2][q]+redA[3][q];
            float Q2 = redB[0][q]+redB[1][q]+redB[2][q]+redB[3][q];
            float m = S*(1.f/512.f);
            float var = Q2*(1.f/512.f) - m*m;
            mean[reg]=m; rstd[reg]=rsqrtf(var + LN_EPS);
        }
        #pragma unroll
        for (int nt=0;nt<8;++nt){
            int col = w*128 + nt*16 + c;
            float gg = g2[col], bb2 = b2[col];
            #pragma unroll
            for (int reg=0;reg<4;++reg){
                int row = rowbase + quad*4 + reg;
                out[(size_t)row*512 + col] = (dacc[nt][reg]-mean[reg])*rstd[reg]*gg + bb2;
            }
        }
    }
}

extern "C" void kernel_launch(void* const* d_in, const int* in_sizes, int n_in,
                              void* d_out, int out_size, void* d_ws, size_t ws_size,
                              hipStream_t stream) {
    (void)in_sizes; (void)n_in; (void)out_size; (void)ws_size;
    const float* x  = (const float*)d_in[0];
    const float* wq = (const float*)d_in[1];
    const float* bq = (const float*)d_in[2];
    const float* wk = (const float*)d_in[3];
    const float* bk = (const float*)d_in[4];
    const float* wv = (const float*)d_in[5];
    const float* bv = (const float*)d_in[6];
    const float* wm = (const float*)d_in[7];
    const float* bm = (const float*)d_in[8];
    const float* g1 = (const float*)d_in[9];
    const float* b1 = (const float*)d_in[10];
    const float* g2 = (const float*)d_in[11];
    const float* b2 = (const float*)d_in[12];

    // ws layout (11.1 MB): bf16 frag-ordered panels + Q/K frags
    u16* x_pB  = (u16*)d_ws;               // 32 bd x 8 s x 16384 u16 = 8 MB
    u16* wv_p  = x_pB + (size_t)4194304;   // 512 KB
    u16* wm_p  = wv_p + 262144;            // 512 KB
    u16* wqk_p = wm_p + 262144;            // 128 KB
    u16* Qb    = wqk_p + 65536;            // 1 MB
    u16* Kb    = Qb + 524288;              // 1 MB
    float* outp = (float*)d_out;

    k0_prep<<<304, 256, 0, stream>>>(x, wq, wk, wv, wm, x_pB, wv_p, wm_p, wqk_p);
    k1_qk  <<<512, 256, 0, stream>>>(x, bq, bk, wqk_p, Qb, Kb);
    k234   <<<512, 256, 0, stream>>>(Qb, Kb, x_pB, wv_p, wm_p, x, bv, g1, b1, bm, g2, b2, outp);
}

// Round 8
// 150.595 us; speedup vs baseline: 1.3887x; 1.3887x over previous
//
#include <hip/hip_runtime.h>
#include <cstdint>

// B,D,H,W,C = 4,8,16,16,512; R=64; F=256; rows=8192; keys/batch=2048.
// Inputs f32, output f32. GEMMs via mfma_f32_16x16x32_bf16, frag-ordered panels.
// K-loops use the proven round-6 barrier-synced staging (sync/glds/sync/mfma);
// k23+k4 fused: y1 never touches global memory.
#define LN_EPS 1e-3f
using u16 = unsigned short;
using u32 = unsigned int;
typedef __attribute__((ext_vector_type(8))) short bh8;   // 8 bf16
typedef __attribute__((ext_vector_type(4))) float f4;    // 4 f32 acc
#define MFMA16(A,B,C) __builtin_amdgcn_mfma_f32_16x16x32_bf16((A),(B),(C),0,0,0)

__device__ __forceinline__ u16 bf16r(float f){
    union{float f;u32 u;} c; c.f=f;
    return (u16)((c.u + 0x7fffu + ((c.u>>16)&1u))>>16);
}
__device__ __forceinline__ u32 pk2(float a, float b){
    return (u32)bf16r(a) | ((u32)bf16r(b)<<16);
}
__device__ __forceinline__ void glds16(const void* g, void* l){
    __builtin_amdgcn_global_load_lds(
        (const __attribute__((address_space(1))) u32*)g,
        (__attribute__((address_space(3))) u32*)l, 16, 0, 0);
}

// ---------------- K0: repack f32 -> bf16 frag-ordered K-panels ----------------
__global__ __launch_bounds__(256) void k0_prep(
    const float* __restrict__ x,  const float* __restrict__ wq, const float* __restrict__ wk,
    const float* __restrict__ wv, const float* __restrict__ wm,
    u16* __restrict__ x_pB, u16* __restrict__ wv_p, u16* __restrict__ wm_p, u16* __restrict__ wqk_p)
{
    const int t = threadIdx.x;
    const int c = t & 15, qn = t >> 4;
    const int quad = qn & 3, ntl = qn >> 2;
    const int blk = blockIdx.x;
    if (blk < 256){
        const int bd = blk >> 3, s = blk & 7;
        const float* src = x + ((size_t)(bd*256 + s*32 + quad*8))*512;
        u16* dst = x_pB + (size_t)(bd*8+s)*16384;
        #pragma unroll
        for (int i=0;i<8;++i){
            int nt = i*4 + ntl, n = nt*16 + c;
            float v[8];
            #pragma unroll
            for (int j=0;j<8;++j) v[j] = src[(size_t)j*512 + n];
            uint4 o; o.x=pk2(v[0],v[1]); o.y=pk2(v[2],v[3]); o.z=pk2(v[4],v[5]); o.w=pk2(v[6],v[7]);
            *(uint4*)&dst[((nt*4+quad)*16 + c)*8] = o;
        }
    } else if (blk < 288){
        const int ism = (blk >= 272);
        const int s = ism ? (blk-272) : (blk-256);
        const float* src = (ism ? wm : wv) + (size_t)(s*32 + quad*8)*512;
        u16* dst = (ism ? wm_p : wv_p) + (size_t)s*16384;
        #pragma unroll
        for (int i=0;i<8;++i){
            int nt = i*4 + ntl, n = nt*16 + c;
            float v[8];
            #pragma unroll
            for (int j=0;j<8;++j) v[j] = src[(size_t)j*512 + n];
            uint4 o; o.x=pk2(v[0],v[1]); o.y=pk2(v[2],v[3]); o.z=pk2(v[4],v[5]); o.w=pk2(v[6],v[7]);
            *(uint4*)&dst[((nt*4+quad)*16 + c)*8] = o;
        }
    } else {
        const int s = blk - 288;
        u16* dst = wqk_p + (size_t)s*4096;
        #pragma unroll
        for (int i=0;i<2;++i){
            int nt = i*4 + ntl, n = nt*16 + c;
            const float* src = (n < 64) ? (wq + (size_t)(s*32 + quad*8)*64 + n)
                                        : (wk + (size_t)(s*32 + quad*8)*64 + (n-64));
            float v[8];
            #pragma unroll
            for (int j=0;j<8;++j) v[j] = src[(size_t)j*64];
            uint4 o; o.x=pk2(v[0],v[1]); o.y=pk2(v[2],v[3]); o.z=pk2(v[4],v[5]); o.w=pk2(v[6],v[7]);
            *(uint4*)&dst[((nt*4+quad)*16 + c)*8] = o;
        }
    }
}

// ---------------- K1: Q/K projection (MFMA) ----------------
// grid 512 (16 rows/block). A staged once (16 KB); wqk panels barrier-synced.
__global__ __launch_bounds__(256) void k1_qk(
    const float* __restrict__ x, const float* __restrict__ bq, const float* __restrict__ bk,
    const u16* __restrict__ wqk_p, u16* __restrict__ Qb, u16* __restrict__ Kb)
{
    __shared__ u16 Asf[8192];      // 16 rows x 512 K, A-frag [s][quad][c][8]
    __shared__ u16 Bsf[4096];      // 8 KB panel
    const int t = threadIdx.x, w = t>>6, lane = t&63, quad = lane>>4, c = lane&15;
    const int rowbase = blockIdx.x << 4;
    // stage full A tile, frag order
    #pragma unroll
    for (int i=0;i<8;++i){
        int idx = t + (i<<8);            // 0..2047 (float4 units)
        int fr = idx >> 7, fc4 = idx & 127;
        float4 xv = *(const float4*)&x[(size_t)(rowbase+fr)*512 + fc4*4];
        uint2 pkv; pkv.x = pk2(xv.x,xv.y); pkv.y = pk2(xv.z,xv.w);
        int s = fc4 >> 3, qd = (fc4 >> 1) & 3, j0 = (fc4 & 1)*4;
        *(uint2*)&Asf[s*512 + (qd*16 + fr)*8 + j0] = pkv;
    }
    f4 acc[2] = { {0.f,0.f,0.f,0.f}, {0.f,0.f,0.f,0.f} };
    for (int s=0;s<16;++s){
        __syncthreads();
        #pragma unroll
        for (int i=0;i<2;++i)
            glds16((const char*)wqk_p + (size_t)s*8192 + (w*2+i)*1024 + lane*16,
                   (char*)Bsf + (w*2+i)*1024);
        __syncthreads();
        bh8 a = *(const bh8*)&Asf[s*512 + (quad*16+c)*8];
        #pragma unroll
        for (int nt=0;nt<2;++nt){
            bh8 b = *(const bh8*)&Bsf[(w*2+nt)*512 + (quad*16+c)*8];
            acc[nt] = MFMA16(a, b, acc[nt]);
        }
    }
    const int rt = blockIdx.x;
    #pragma unroll
    for (int nt=0;nt<2;++nt){
        int cqk = w*32 + nt*16 + c;
        bool isQ = (cqk < 64);
        int r = isQ ? cqk : (cqk - 64);
        float bias = isQ ? bq[r] : bk[r];
        int kh = r>>5, q2 = (r>>3)&3, j = r&7;
        u16* dstb = (isQ ? Qb : Kb) + (size_t)((rt*2 + kh)*4 + q2)*128 + j;
        #pragma unroll
        for (int reg=0;reg<4;++reg){
            int cp = quad*4 + reg;
            dstb[cp*8] = bf16r(acc[nt][reg] + bias);
        }
    }
}

// ---------------- K234: attn + LN + MLP + LN, fused, barrier-synced loops ----------------
// grid 512 = (b,d,ft16), block 256 (4 waves). y1 stays in regs (cacc) + zf frags.
__global__ __launch_bounds__(256) void k234(
    const u16* __restrict__ Qb, const u16* __restrict__ Kb,
    const u16* __restrict__ x_pB, const u16* __restrict__ wv_p, const u16* __restrict__ wm_p,
    const float* __restrict__ x, const float* __restrict__ bv,
    const float* __restrict__ g1, const float* __restrict__ b1,
    const float* __restrict__ bm, const float* __restrict__ g2, const float* __restrict__ b2,
    float* __restrict__ out)
{
    __shared__ u16 Bs[16384];       // 32 KB staging (all phases)
    __shared__ u16 zf[8192];        // 16 KB: z frags, then y1 frags (A-op over K=512)
    __shared__ u16 a2f[4096];       // 8 KB (A-op over K=256)
    __shared__ u16 qsf[1024];       // 2 KB
    __shared__ float redA[4][16], redB[4][16];
    const int t = threadIdx.x, w = t>>6, lane = t&63, quad = lane>>4, c = lane&15;
    const int b = blockIdx.x >> 7, rem = blockIdx.x & 127, d = rem >> 4, ft = rem & 15;
    const int bd = b*8 + d, rowbase = (bd<<8) + (ft<<4), rt = rowbase >> 4;
    const char* Kbase = (const char*)Kb + (size_t)b*262144;
    const char* xpb   = (const char*)x_pB + (size_t)bd*262144;

    if (w < 2) glds16((const char*)Qb + (size_t)rt*2048 + w*1024 + lane*16, (char*)qsf + w*1024);
    __syncthreads();
    bh8 aq0 = *(const bh8*)&qsf[(quad*16+c)*8];
    bh8 aq1 = *(const bh8*)&qsf[512 + (quad*16+c)*8];

    float lp[4] = {0.f,0.f,0.f,0.f};
    float a2r[4][2][2];
    #pragma unroll
    for (int r=0;r<4;++r){ a2r[r][0][0]=0.f; a2r[r][0][1]=0.f; a2r[r][1][0]=0.f; a2r[r][1][1]=0.f; }

    // ---- Phase A: scores + exp + g-fold (16 chunks of 128 keys)
    for (int cc=0; cc<16; ++cc){
        if (cc) __syncthreads();
        #pragma unroll
        for (int i=0;i<4;++i)
            glds16(Kbase + (size_t)cc*16384 + (w*4+i)*1024 + lane*16, (char*)Bs + (w*4+i)*1024);
        __syncthreads();
        f4 sa[2] = { {0.f,0.f,0.f,0.f}, {0.f,0.f,0.f,0.f} };
        #pragma unroll
        for (int kt=0;kt<2;++kt){
            bh8 b0 = *(const bh8*)&Bs[(w*2+kt)*1024 +       (quad*16+c)*8];
            bh8 b1v= *(const bh8*)&Bs[(w*2+kt)*1024 + 512 + (quad*16+c)*8];
            sa[kt] = MFMA16(aq0, b0, sa[kt]);
            sa[kt] = MFMA16(aq1, b1v, sa[kt]);
        }
        const int h = cc & 1;
        #pragma unroll
        for (int kt=0;kt<2;++kt)
            #pragma unroll
            for (int reg=0;reg<4;++reg){
                float e = __expf(sa[kt][reg]);
                lp[reg] += e;
                a2r[reg][h][kt] += e;
            }
    }
    // softmax denominator
    #pragma unroll
    for (int reg=0;reg<4;++reg){
        float v = lp[reg];
        v += __shfl_xor(v,1,64); v += __shfl_xor(v,2,64);
        v += __shfl_xor(v,4,64); v += __shfl_xor(v,8,64);
        lp[reg] = v;
    }
    if (c==0){
        #pragma unroll
        for (int reg=0;reg<4;++reg) redA[w][quad*4+reg] = lp[reg];
    }
    __syncthreads();
    float fac[4];
    #pragma unroll
    for (int reg=0;reg<4;++reg){
        int q = quad*4+reg;
        fac[reg] = 1.f/(redA[0][q]+redA[1][q]+redA[2][q]+redA[3][q]);
    }
    #pragma unroll
    for (int reg=0;reg<4;++reg){
        int q = quad*4+reg;
        #pragma unroll
        for (int h=0;h<2;++h)
            #pragma unroll
            for (int kt=0;kt<2;++kt){
                int j = h*128 + (w*2+kt)*16 + c;
                a2f[(j>>5)*512 + (((j>>3)&3)*16 + q)*8 + (j&7)] = bf16r(a2r[reg][h][kt]*fac[reg]);
            }
    }
    __syncthreads();

    // ---- Phase B: z = a2 @ x_bd (K=256, 8 steps)
    f4 zacc[8];
    #pragma unroll
    for (int nt=0;nt<8;++nt) zacc[nt] = (f4){0.f,0.f,0.f,0.f};
    for (int s=0;s<8;++s){
        if (s) __syncthreads();
        #pragma unroll
        for (int i=0;i<8;++i)
            glds16(xpb + (size_t)s*32768 + (w*8+i)*1024 + lane*16, (char*)Bs + (w*8+i)*1024);
        __syncthreads();
        bh8 a = *(const bh8*)&a2f[s*512 + (quad*16+c)*8];
        #pragma unroll
        for (int nt=0;nt<8;++nt){
            bh8 bb = *(const bh8*)&Bs[((w*8+nt)*4 + quad)*128 + c*8];
            zacc[nt] = MFMA16(a, bb, zacc[nt]);
        }
    }
    // z -> zf (A-frag order)
    __syncthreads();
    #pragma unroll
    for (int nt=0;nt<8;++nt)
        #pragma unroll
        for (int reg=0;reg<4;++reg){
            int col = w*128 + nt*16 + c;
            zf[(col>>5)*512 + (((col>>3)&3)*16 + quad*4+reg)*8 + (col&7)] = bf16r(zacc[nt][reg]);
        }
    __syncthreads();

    // ---- Phase C: attn = z @ wv (K=512, 16 steps)
    f4 cacc[8];
    #pragma unroll
    for (int nt=0;nt<8;++nt) cacc[nt] = (f4){0.f,0.f,0.f,0.f};
    for (int s=0;s<16;++s){
        if (s) __syncthreads();
        #pragma unroll
        for (int i=0;i<8;++i)
            glds16((const char*)wv_p + (size_t)s*32768 + (w*8+i)*1024 + lane*16, (char*)Bs + (w*8+i)*1024);
        __syncthreads();
        bh8 a = *(const bh8*)&zf[s*512 + (quad*16+c)*8];
        #pragma unroll
        for (int nt=0;nt<8;++nt){
            bh8 bb = *(const bh8*)&Bs[((w*8+nt)*4 + quad)*128 + c*8];
            cacc[nt] = MFMA16(a, bb, cacc[nt]);
        }
    }
    // epilogue 1: + bv + x residual, LN -> y1 kept in cacc (f32) and zf (bf16 A-frags)
    {
        float sv[4] = {0.f,0.f,0.f,0.f}, qv2[4] = {0.f,0.f,0.f,0.f};
        #pragma unroll
        for (int nt=0;nt<8;++nt){
            int col = w*128 + nt*16 + c;
            float bvv = bv[col];
            #pragma unroll
            for (int reg=0;reg<4;++reg){
                int row = rowbase + quad*4 + reg;
                float val = cacc[nt][reg] + bvv + x[(size_t)row*512 + col];
                cacc[nt][reg] = val;
                sv[reg] += val; qv2[reg] = fmaf(val,val,qv2[reg]);
            }
        }
        #pragma unroll
        for (int reg=0;reg<4;++reg){
            float s1=sv[reg], s2=qv2[reg];
            s1 += __shfl_xor(s1,1,64); s2 += __shfl_xor(s2,1,64);
            s1 += __shfl_xor(s1,2,64); s2 += __shfl_xor(s2,2,64);
            s1 += __shfl_xor(s1,4,64); s2 += __shfl_xor(s2,4,64);
            s1 += __shfl_xor(s1,8,64); s2 += __shfl_xor(s2,8,64);
            sv[reg]=s1; qv2[reg]=s2;
        }
        if (c==0){
            #pragma unroll
            for (int reg=0;reg<4;++reg){ redA[w][quad*4+reg]=sv[reg]; redB[w][quad*4+reg]=qv2[reg]; }
        }
        __syncthreads();   // also: all phase-C zf reads done before zf overwrite below
        float mean[4], rstd[4];
        #pragma unroll
        for (int reg=0;reg<4;++reg){
            int q = quad*4+reg;
            float S  = redA[0][q]+redA[1][q]+redA[2][q]+redA[3][q];
            float Q2 = redB[0][q]+redB[1][q]+redB[2][q]+redB[3][q];
            float m = S*(1.f/512.f);
            float var = Q2*(1.f/512.f) - m*m;
            mean[reg]=m; rstd[reg]=rsqrtf(var + LN_EPS);
        }
        #pragma unroll
        for (int nt=0;nt<8;++nt){
            int col = w*128 + nt*16 + c;
            float gg = g1[col], bb1 = b1[col];
            #pragma unroll
            for (int reg=0;reg<4;++reg){
                float y = (cacc[nt][reg]-mean[reg])*rstd[reg]*gg + bb1;
                cacc[nt][reg] = y;
                zf[(col>>5)*512 + (((col>>3)&3)*16 + quad*4+reg)*8 + (col&7)] = bf16r(y);
            }
        }
        __syncthreads();   // zf (y1 frags) visible to all waves
    }

    // ---- Phase D: mlp = y1 @ wm (K=512, 16 steps)
    f4 dacc[8];
    #pragma unroll
    for (int nt=0;nt<8;++nt) dacc[nt] = (f4){0.f,0.f,0.f,0.f};
    for (int s=0;s<16;++s){
        if (s) __syncthreads();
        #pragma unroll
        for (int i=0;i<8;++i)
            glds16((const char*)wm_p + (size_t)s*32768 + (w*8+i)*1024 + lane*16, (char*)Bs + (w*8+i)*1024);
        __syncthreads();
        bh8 a = *(const bh8*)&zf[s*512 + (quad*16+c)*8];
        #pragma unroll
        for (int nt=0;nt<8;++nt){
            bh8 bb = *(const bh8*)&Bs[((w*8+nt)*4 + quad)*128 + c*8];
            dacc[nt] = MFMA16(a, bb, dacc[nt]);
        }
    }
    // epilogue 2: relu(+bm) + y1 residual, LN -> out
    {
        float sv[4] = {0.f,0.f,0.f,0.f}, qv2[4] = {0.f,0.f,0.f,0.f};
        #pragma unroll
        for (int nt=0;nt<8;++nt){
            int col = w*128 + nt*16 + c;
            float bmv = bm[col];
            #pragma unroll
            for (int reg=0;reg<4;++reg){
                float hh = fmaxf(dacc[nt][reg]+bmv, 0.f) + cacc[nt][reg];
                dacc[nt][reg] = hh;
                sv[reg] += hh; qv2[reg] = fmaf(hh,hh,qv2[reg]);
            }
        }
        #pragma unroll
        for (int reg=0;reg<4;++reg){
            float s1=sv[reg], s2=qv2[reg];
            s1 += __shfl_xor(s1,1,64); s2 += __shfl_xor(s2,1,64);
            s1 += __shfl_xor(s1,2,64); s2 += __shfl_xor(s2,2,64);
            s1 += __shfl_xor(s1,4,64); s2 += __shfl_xor(s2,4,64);
            s1 += __shfl_xor(s1,8,64); s2 += __shfl_xor(s2,8,64);
            sv[reg]=s1; qv2[reg]=s2;
        }
        __syncthreads();   // phase-D reads of redA done (phase A) — protect reuse
        if (c==0){
            #pragma unroll
            for (int reg=0;reg<4;++reg){ redA[w][quad*4+reg]=sv[reg]; redB[w][quad*4+reg]=qv2[reg]; }
        }
        __syncthreads();
        float mean[4], rstd[4];
        #pragma unroll
        for (int reg=0;reg<4;++reg){
            int q = quad*4+reg;
            float S  = redA[0][q]+redA[1][q]+redA[2][q]+redA[3][q];
            float Q2 = redB[0][q]+redB[1][q]+redB[2][q]+redB[3][q];
            float m = S*(1.f/512.f);
            float var = Q2*(1.f/512.f) - m*m;
            mean[reg]=m; rstd[reg]=rsqrtf(var + LN_EPS);
        }
        #pragma unroll
        for (int nt=0;nt<8;++nt){
            int col = w*128 + nt*16 + c;
            float gg = g2[col], bb2 = b2[col];
            #pragma unroll
            for (int reg=0;reg<4;++reg){
                int row = rowbase + quad*4 + reg;
                out[(size_t)row*512 + col] = (dacc[nt][reg]-mean[reg])*rstd[reg]*gg + bb2;
            }
        }
    }
}

extern "C" void kernel_launch(void* const* d_in, const int* in_sizes, int n_in,
                              void* d_out, int out_size, void* d_ws, size_t ws_size,
                              hipStream_t stream) {
    (void)in_sizes; (void)n_in; (void)out_size; (void)ws_size;
    const float* x  = (const float*)d_in[0];
    const float* wq = (const float*)d_in[1];
    const float* bq = (const float*)d_in[2];
    const float* wk = (const float*)d_in[3];
    const float* bk = (const float*)d_in[4];
    const float* wv = (const float*)d_in[5];
    const float* bv = (const float*)d_in[6];
    const float* wm = (const float*)d_in[7];
    const float* bm = (const float*)d_in[8];
    const float* g1 = (const float*)d_in[9];
    const float* b1 = (const float*)d_in[10];
    const float* g2 = (const float*)d_in[11];
    const float* b2 = (const float*)d_in[12];

    // ws layout (11.1 MB): bf16 frag-ordered panels + Q/K frags
    u16* x_pB  = (u16*)d_ws;               // 8 MB
    u16* wv_p  = x_pB + (size_t)4194304;   // 512 KB
    u16* wm_p  = wv_p + 262144;            // 512 KB
    u16* wqk_p = wm_p + 262144;            // 128 KB
    u16* Qb    = wqk_p + 65536;            // 1 MB
    u16* Kb    = Qb + 524288;              // 1 MB
    float* outp = (float*)d_out;

    k0_prep<<<304, 256, 0, stream>>>(x, wq, wk, wv, wm, x_pB, wv_p, wm_p, wqk_p);
    k1_qk  <<<512, 256, 0, stream>>>(x, bq, bk, wqk_p, Qb, Kb);
    k234   <<<512, 256, 0, stream>>>(Qb, Kb, x_pB, wv_p, wm_p, x, bv, g1, b1, bm, g2, b2, outp);
}